// Round 1
// baseline (575.498 us; speedup 1.0000x reference)
//
#include <hip/hip_runtime.h>
#include <math.h>

#define BB 64
#define TT 128
#define HH 16
#define GG 64      // 4*H
#define IN0_ 65
#define VV 32000
#define NROWS (BB*TT)   // 8192

__device__ __forceinline__ float sigmoidf_(float x) {
    return 1.0f / (1.0f + __expf(-x));
}

// ---------------- Kernel 1: embedding gather + layer0 input projection ----------------
// grid = NROWS blocks, 64 threads. xp0[r*64+g] = (b_ih0+b_hh0)[g] + dot(inp[65], W_ih0[g,:])
__global__ void embed_xproj0(const float* __restrict__ x, const float* __restrict__ emb,
                             const float* __restrict__ Wih0, const float* __restrict__ bih0,
                             const float* __restrict__ bhh0, float* __restrict__ xp0) {
    __shared__ float inp[IN0_];
    const int r = blockIdx.x;        // 0..8191  (b*T + t)
    const int g = threadIdx.x;       // 0..63
    const float* xr = x + r * 9;
    if (g < 8) {
        int idx = (int)xr[g];                 // categorical index, exact in fp32
        const float* er = emb + (size_t)idx * 8;
        float4 a = *reinterpret_cast<const float4*>(er);
        float4 b = *reinterpret_cast<const float4*>(er + 4);
        int base = g * 8;
        inp[base + 0] = a.x; inp[base + 1] = a.y; inp[base + 2] = a.z; inp[base + 3] = a.w;
        inp[base + 4] = b.x; inp[base + 5] = b.y; inp[base + 6] = b.z; inp[base + 7] = b.w;
    } else if (g == 8) {
        inp[64] = xr[8];                      // numeric feature
    }
    __syncthreads();
    float acc = bih0[g] + bhh0[g];
    const float* wr = Wih0 + g * IN0_;
    #pragma unroll
    for (int k = 0; k < IN0_; ++k) acc += inp[k] * wr[k];
    xp0[r * GG + g] = acc;
}

// ---------------- Kernel 2: sequential 2-layer LSTM recurrence ----------------
// grid = B blocks, 64 threads (one wave). Lane g owns gate g of both layers.
__global__ void recurrence(const float* __restrict__ xp0,
                           const float* __restrict__ h0in, const float* __restrict__ c0in,
                           const float* __restrict__ Whh0,
                           const float* __restrict__ Wih1, const float* __restrict__ Whh1,
                           const float* __restrict__ bih1, const float* __restrict__ bhh1,
                           float* __restrict__ y1, float* __restrict__ outTail) {
    const int b = blockIdx.x;
    const int g = threadIdx.x;   // 0..63
    __shared__ float h0s[HH], h1s[HH], gs[GG];

    float w0[HH], wi1[HH], w1[HH];
    #pragma unroll
    for (int k = 0; k < HH; ++k) {
        w0[k]  = Whh0[g * HH + k];
        wi1[k] = Wih1[g * HH + k];
        w1[k]  = Whh1[g * HH + k];
    }
    const float bias1 = bih1[g] + bhh1[g];

    float c0v = 0.0f, c1v = 0.0f;
    if (g < HH) {
        h0s[g] = h0in[b * HH + g];                 // layer 0 initial h
        h1s[g] = h0in[BB * HH + b * HH + g];       // layer 1 initial h
        c0v    = c0in[b * HH + g];
        c1v    = c0in[BB * HH + b * HH + g];
    }
    __syncthreads();

    for (int t = 0; t < TT; ++t) {
        // layer 0 gates
        float acc = xp0[(b * TT + t) * GG + g];
        #pragma unroll
        for (int k = 0; k < HH; ++k) acc += h0s[k] * w0[k];
        gs[g] = acc;
        __syncthreads();
        if (g < HH) {
            float iv = gs[g], fv = gs[g + 16], gv = gs[g + 32], ov = gs[g + 48];
            c0v = sigmoidf_(fv) * c0v + sigmoidf_(iv) * tanhf(gv);
            h0s[g] = sigmoidf_(ov) * tanhf(c0v);
        }
        __syncthreads();
        // layer 1 gates (input proj fused: y0 = h0s just updated)
        float acc1 = bias1;
        #pragma unroll
        for (int k = 0; k < HH; ++k) acc1 += h0s[k] * wi1[k] + h1s[k] * w1[k];
        gs[g] = acc1;
        __syncthreads();
        if (g < HH) {
            float iv = gs[g], fv = gs[g + 16], gv = gs[g + 32], ov = gs[g + 48];
            c1v = sigmoidf_(fv) * c1v + sigmoidf_(iv) * tanhf(gv);
            float h = sigmoidf_(ov) * tanhf(c1v);
            h1s[g] = h;
            y1[(b * TT + t) * HH + g] = h;
        }
        __syncthreads();
    }

    if (g < HH) {
        // tail: hN (2,B,H) then cN (2,B,H)
        outTail[b * HH + g]                 = h0s[g];
        outTail[BB * HH + b * HH + g]       = h1s[g];
        outTail[2 * BB * HH + b * HH + g]   = c0v;
        outTail[3 * BB * HH + b * HH + g]   = c1v;
    }
}

// ---------------- Kernel 3: FC head (write-bound) ----------------
// block = 256 threads; each thread owns 4 consecutive v; 16 rows per block.
__global__ __launch_bounds__(256) void fc_kernel(const float* __restrict__ y1,
                          const float* __restrict__ fcw, const float* __restrict__ fcb,
                          float* __restrict__ out) {
    const int R = 16;
    __shared__ float ys[R * HH];                  // 256 floats
    const int tid  = threadIdx.x;
    const int v0   = blockIdx.x * 1024 + tid * 4;
    const int row0 = blockIdx.y * R;

    ys[tid] = y1[row0 * HH + tid];                // R*H == 256 == blockDim
    __syncthreads();

    if (v0 >= VV) return;

    float w[4][HH];
    #pragma unroll
    for (int j = 0; j < 4; ++j) {
        const float4* wp = reinterpret_cast<const float4*>(fcw + (size_t)(v0 + j) * HH);
        float4 a = wp[0], b = wp[1], c = wp[2], d = wp[3];
        w[j][0]=a.x; w[j][1]=a.y; w[j][2]=a.z; w[j][3]=a.w;
        w[j][4]=b.x; w[j][5]=b.y; w[j][6]=b.z; w[j][7]=b.w;
        w[j][8]=c.x; w[j][9]=c.y; w[j][10]=c.z; w[j][11]=c.w;
        w[j][12]=d.x; w[j][13]=d.y; w[j][14]=d.z; w[j][15]=d.w;
    }
    const float4 bias = *reinterpret_cast<const float4*>(fcb + v0);

    for (int r = 0; r < R; ++r) {
        float a0 = bias.x, a1 = bias.y, a2 = bias.z, a3 = bias.w;
        #pragma unroll
        for (int k = 0; k < HH; ++k) {
            float yk = ys[r * HH + k];
            a0 += yk * w[0][k];
            a1 += yk * w[1][k];
            a2 += yk * w[2][k];
            a3 += yk * w[3][k];
        }
        float4 o = make_float4(a0, a1, a2, a3);
        *reinterpret_cast<float4*>(out + (size_t)(row0 + r) * VV + v0) = o;
    }
}

extern "C" void kernel_launch(void* const* d_in, const int* in_sizes, int n_in,
                              void* d_out, int out_size, void* d_ws, size_t ws_size,
                              hipStream_t stream) {
    const float* x    = (const float*)d_in[0];
    const float* h0   = (const float*)d_in[1];
    const float* c0   = (const float*)d_in[2];
    const float* emb  = (const float*)d_in[3];
    const float* Wih0 = (const float*)d_in[4];
    const float* Whh0 = (const float*)d_in[5];
    const float* bih0 = (const float*)d_in[6];
    const float* bhh0 = (const float*)d_in[7];
    const float* Wih1 = (const float*)d_in[8];
    const float* Whh1 = (const float*)d_in[9];
    const float* bih1 = (const float*)d_in[10];
    const float* bhh1 = (const float*)d_in[11];
    const float* fcw  = (const float*)d_in[12];
    const float* fcb  = (const float*)d_in[13];

    float* out = (float*)d_out;
    float* xp0 = (float*)d_ws;                   // NROWS*64 floats = 2 MB
    float* y1  = xp0 + (size_t)NROWS * GG;       // NROWS*16 floats = 512 KB
    float* outTail = out + (size_t)NROWS * VV;   // hN then cN

    embed_xproj0<<<NROWS, 64, 0, stream>>>(x, emb, Wih0, bih0, bhh0, xp0);
    recurrence<<<BB, 64, 0, stream>>>(xp0, h0, c0, Whh0, Wih1, Whh1, bih1, bhh1, y1, outTail);
    fc_kernel<<<dim3(32, NROWS / 16), 256, 0, stream>>>(y1, fcw, fcb, out);
}

// Round 3
// 316.061 us; speedup vs baseline: 1.8208x; 1.8208x over previous
//
#include <hip/hip_runtime.h>
#include <math.h>

#define BB 64
#define TT 128
#define HH 16
#define GG 64      // 4*H
#define IN0_ 65
#define VV 32000
#define NROWS (BB*TT)   // 8192

typedef float f32x4 __attribute__((ext_vector_type(4)));

__device__ __forceinline__ float sigf(float x) {
    return 1.0f / (1.0f + __expf(-x));
}
__device__ __forceinline__ float tanhfast(float x) {
    // tanh(x) = 1 - 2/(exp(2x)+1); handles +-inf saturation correctly
    return 1.0f - 2.0f / (__expf(2.0f * x) + 1.0f);
}

// ---------------- Kernel 1: embedding gather + layer0 input projection ----------------
__global__ void embed_xproj0(const float* __restrict__ x, const float* __restrict__ emb,
                             const float* __restrict__ Wih0, const float* __restrict__ bih0,
                             const float* __restrict__ bhh0, float* __restrict__ xp0) {
    __shared__ float inp[IN0_];
    const int r = blockIdx.x;        // 0..8191  (b*T + t)
    const int g = threadIdx.x;       // 0..63
    const float* xr = x + r * 9;
    if (g < 8) {
        int idx = (int)xr[g];
        const float* er = emb + (size_t)idx * 8;
        float4 a = *reinterpret_cast<const float4*>(er);
        float4 b = *reinterpret_cast<const float4*>(er + 4);
        int base = g * 8;
        inp[base + 0] = a.x; inp[base + 1] = a.y; inp[base + 2] = a.z; inp[base + 3] = a.w;
        inp[base + 4] = b.x; inp[base + 5] = b.y; inp[base + 6] = b.z; inp[base + 7] = b.w;
    } else if (g == 8) {
        inp[64] = xr[8];
    }
    __syncthreads();
    float acc = bih0[g] + bhh0[g];
    const float* wr = Wih0 + g * IN0_;
    #pragma unroll
    for (int k = 0; k < IN0_; ++k) acc += inp[k] * wr[k];
    xp0[r * GG + g] = acc;
}

// ---------------- Kernel 2: wave-synchronous 2-layer LSTM recurrence ----------------
// grid = B blocks, one 64-lane wave each. Lane g owns gate g; every lane also
// redundantly tracks the (g&15)-th h/c of both layers so gate math is divergence-free.
// No LDS, no barriers — all cross-lane via __shfl.
__global__ __launch_bounds__(64) void recurrence(const float* __restrict__ xp0,
                           const float* __restrict__ h0in, const float* __restrict__ c0in,
                           const float* __restrict__ Whh0,
                           const float* __restrict__ Wih1, const float* __restrict__ Whh1,
                           const float* __restrict__ bih1, const float* __restrict__ bhh1,
                           float* __restrict__ y1, float* __restrict__ outTail) {
    const int b = blockIdx.x;
    const int g = threadIdx.x;       // 0..63
    const int j = g & 15;            // h-index this lane mirrors

    float w0[HH], wi1[HH], w1[HH];
    #pragma unroll
    for (int k = 0; k < HH; ++k) {
        w0[k]  = Whh0[g * HH + k];
        wi1[k] = Wih1[g * HH + k];
        w1[k]  = Whh1[g * HH + k];
    }
    const float bias1 = bih1[g] + bhh1[g];

    // all lanes load the state for index j (broadcast-friendly, L1 hit)
    float h0v = h0in[b * HH + j];
    float h1v = h0in[BB * HH + b * HH + j];
    float c0v = c0in[b * HH + j];
    float c1v = c0in[BB * HH + b * HH + j];

    const float* xprow = xp0 + (size_t)b * TT * GG + g;
    float xp_cur = xprow[0];

    for (int t = 0; t < TT; ++t) {
        // prefetch next step's input projection (buffer has one pad row)
        float xp_next = xprow[(t + 1) * GG];

        // ---- layer 0 gates ----
        float acc = xp_cur;
        #pragma unroll
        for (int k = 0; k < HH; ++k) acc += __shfl(h0v, k) * w0[k];
        float iv = __shfl(acc, j);
        float fv = __shfl(acc, j + 16);
        float gv = __shfl(acc, j + 32);
        float ov = __shfl(acc, j + 48);
        c0v = sigf(fv) * c0v + sigf(iv) * tanhfast(gv);
        h0v = sigf(ov) * tanhfast(c0v);

        // ---- layer 1 gates ----
        float acc1 = bias1;
        #pragma unroll
        for (int k = 0; k < HH; ++k)
            acc1 += __shfl(h0v, k) * wi1[k] + __shfl(h1v, k) * w1[k];
        float iv1 = __shfl(acc1, j);
        float fv1 = __shfl(acc1, j + 16);
        float gv1 = __shfl(acc1, j + 32);
        float ov1 = __shfl(acc1, j + 48);
        c1v = sigf(fv1) * c1v + sigf(iv1) * tanhfast(gv1);
        h1v = sigf(ov1) * tanhfast(c1v);

        if (g < HH) y1[(size_t)(b * TT + t) * HH + g] = h1v;
        xp_cur = xp_next;
    }

    if (g < HH) {
        outTail[b * HH + g]               = h0v;
        outTail[BB * HH + b * HH + g]     = h1v;
        outTail[2 * BB * HH + b * HH + g] = c0v;
        outTail[3 * BB * HH + b * HH + g] = c1v;
    }
}

// ---------------- Kernel 3: FC head (write-bound) ----------------
__global__ __launch_bounds__(256) void fc_kernel(const float* __restrict__ y1,
                          const float* __restrict__ fcw, const float* __restrict__ fcb,
                          float* __restrict__ out) {
    __shared__ float ys[16 * HH];                 // 16 rows staged, 256 floats
    const int tid  = threadIdx.x;
    const int v0   = blockIdx.x * 1024 + tid * 4;
    const int row0 = blockIdx.y * 16;

    ys[tid] = y1[row0 * HH + tid];
    __syncthreads();

    if (v0 >= VV) return;

    float w[4][HH];
    #pragma unroll
    for (int jj = 0; jj < 4; ++jj) {
        const float4* wp = reinterpret_cast<const float4*>(fcw + (size_t)(v0 + jj) * HH);
        float4 a = wp[0], b = wp[1], c = wp[2], d = wp[3];
        w[jj][0]=a.x; w[jj][1]=a.y; w[jj][2]=a.z; w[jj][3]=a.w;
        w[jj][4]=b.x; w[jj][5]=b.y; w[jj][6]=b.z; w[jj][7]=b.w;
        w[jj][8]=c.x; w[jj][9]=c.y; w[jj][10]=c.z; w[jj][11]=c.w;
        w[jj][12]=d.x; w[jj][13]=d.y; w[jj][14]=d.z; w[jj][15]=d.w;
    }
    const float4 bias = *reinterpret_cast<const float4*>(fcb + v0);
    const f32x4* ysv = reinterpret_cast<const f32x4*>(ys);

    float* orow = out + (size_t)row0 * VV + v0;
    #pragma unroll 4
    for (int r = 0; r < 16; ++r) {
        f32x4 y0 = ysv[r * 4 + 0];
        f32x4 y1v = ysv[r * 4 + 1];
        f32x4 y2 = ysv[r * 4 + 2];
        f32x4 y3 = ysv[r * 4 + 3];
        float a0 = bias.x, a1 = bias.y, a2 = bias.z, a3 = bias.w;
        #pragma unroll
        for (int jj = 0; jj < 4; ++jj) {
            float* wj = w[jj];
            float acc = y0.x*wj[0] + y0.y*wj[1] + y0.z*wj[2] + y0.w*wj[3]
                      + y1v.x*wj[4] + y1v.y*wj[5] + y1v.z*wj[6] + y1v.w*wj[7]
                      + y2.x*wj[8] + y2.y*wj[9] + y2.z*wj[10] + y2.w*wj[11]
                      + y3.x*wj[12] + y3.y*wj[13] + y3.z*wj[14] + y3.w*wj[15];
            if (jj == 0) a0 += acc;
            else if (jj == 1) a1 += acc;
            else if (jj == 2) a2 += acc;
            else a3 += acc;
        }
        f32x4 o;
        o.x = a0; o.y = a1; o.z = a2; o.w = a3;
        __builtin_nontemporal_store(o, reinterpret_cast<f32x4*>(orow));
        orow += VV;
    }
}

extern "C" void kernel_launch(void* const* d_in, const int* in_sizes, int n_in,
                              void* d_out, int out_size, void* d_ws, size_t ws_size,
                              hipStream_t stream) {
    const float* x    = (const float*)d_in[0];
    const float* h0   = (const float*)d_in[1];
    const float* c0   = (const float*)d_in[2];
    const float* emb  = (const float*)d_in[3];
    const float* Wih0 = (const float*)d_in[4];
    const float* Whh0 = (const float*)d_in[5];
    const float* bih0 = (const float*)d_in[6];
    const float* bhh0 = (const float*)d_in[7];
    const float* Wih1 = (const float*)d_in[8];
    const float* Whh1 = (const float*)d_in[9];
    const float* bih1 = (const float*)d_in[10];
    const float* bhh1 = (const float*)d_in[11];
    const float* fcw  = (const float*)d_in[12];
    const float* fcb  = (const float*)d_in[13];

    float* out = (float*)d_out;
    float* xp0 = (float*)d_ws;                          // NROWS*64 floats (+1 pad row)
    float* y1  = xp0 + (size_t)NROWS * GG + GG;         // NROWS*16 floats
    float* outTail = out + (size_t)NROWS * VV;          // hN then cN

    embed_xproj0<<<NROWS, 64, 0, stream>>>(x, emb, Wih0, bih0, bhh0, xp0);
    recurrence<<<BB, 64, 0, stream>>>(xp0, h0, c0, Whh0, Wih1, Whh1, bih1, bhh1, y1, outTail);
    fc_kernel<<<dim3(32, NROWS / 16), 256, 0, stream>>>(y1, fcw, fcb, out);
}

// Round 4
// 290.560 us; speedup vs baseline: 1.9807x; 1.0878x over previous
//
#include <hip/hip_runtime.h>
#include <math.h>

#define BB 64
#define TT 128
#define HH 16
#define GG 64      // 4*H
#define IN0_ 65
#define VV 32000
#define NROWS (BB*TT)   // 8192
#define RPB 16          // rows per embed block

typedef float f32x4 __attribute__((ext_vector_type(4)));

__device__ __forceinline__ float sigf(float x) {
    return 1.0f / (1.0f + __expf(-x));
}
__device__ __forceinline__ float tanhfast(float x) {
    return 1.0f - 2.0f / (__expf(2.0f * x) + 1.0f);
}

// ---------------- Kernel 1: embedding gather + layer0 input projection ----------------
// 512 blocks x 256 threads; each block does 16 (b,t) rows. Wih0 staged in LDS
// (row stride 65 -> scalar lane-g reads are bank-conflict-free). Each wave
// computes 4 rows k-major so each W element is read once per 4 rows.
__global__ __launch_bounds__(256) void embed_xproj0(const float* __restrict__ x,
                             const float* __restrict__ emb,
                             const float* __restrict__ Wih0, const float* __restrict__ bih0,
                             const float* __restrict__ bhh0, float* __restrict__ xp0) {
    __shared__ float wsh[GG * IN0_];      // 4160 floats
    __shared__ float insh[RPB][68];       // 68: float4-aligned row stride
    const int tid  = threadIdx.x;
    const int row0 = blockIdx.x * RPB;

    for (int i = tid; i < GG * IN0_; i += 256) wsh[i] = Wih0[i];

    {   // gather embeddings: 128 (row,feat) pairs, 2 threads each (float4 halves)
        int p = tid >> 1, half = tid & 1;
        int r = p >> 3, f = p & 7;
        int idx = (int)x[(size_t)(row0 + r) * 9 + f];
        const float* er = emb + (size_t)idx * 8 + half * 4;
        float4 e = *reinterpret_cast<const float4*>(er);
        float* d = &insh[r][f * 8 + half * 4];
        d[0] = e.x; d[1] = e.y; d[2] = e.z; d[3] = e.w;
    }
    if (tid < RPB) insh[tid][64] = x[(size_t)(row0 + tid) * 9 + 8];
    __syncthreads();

    const int wave = tid >> 6, g = tid & 63;
    const float bias = bih0[g] + bhh0[g];
    float acc0 = bias, acc1 = bias, acc2 = bias, acc3 = bias;
    const float* wrow = &wsh[g * IN0_];
    const float* i0 = &insh[wave * 4 + 0][0];
    const float* i1 = &insh[wave * 4 + 1][0];
    const float* i2 = &insh[wave * 4 + 2][0];
    const float* i3 = &insh[wave * 4 + 3][0];
    #pragma unroll
    for (int k = 0; k < IN0_; ++k) {
        float wk = wrow[k];
        acc0 += i0[k] * wk;
        acc1 += i1[k] * wk;
        acc2 += i2[k] * wk;
        acc3 += i3[k] * wk;
    }
    xp0[(size_t)(row0 + wave * 4 + 0) * GG + g] = acc0;
    xp0[(size_t)(row0 + wave * 4 + 1) * GG + g] = acc1;
    xp0[(size_t)(row0 + wave * 4 + 2) * GG + g] = acc2;
    xp0[(size_t)(row0 + wave * 4 + 3) * GG + g] = acc3;
}

// ---------------- Kernel 2: wave-synchronous pipelined 2-layer LSTM ----------------
// One 64-lane wave per batch. Loop body computes layer1(t) and layer0(t+1)
// concurrently (both depend only on h0(t), h1(t-1)) -> ~halved critical path.
__global__ __launch_bounds__(64) void recurrence(const float* __restrict__ xp0,
                           const float* __restrict__ h0in, const float* __restrict__ c0in,
                           const float* __restrict__ Whh0,
                           const float* __restrict__ Wih1, const float* __restrict__ Whh1,
                           const float* __restrict__ bih1, const float* __restrict__ bhh1,
                           float* __restrict__ y1, float* __restrict__ outTail) {
    const int b = blockIdx.x;
    const int g = threadIdx.x;
    const int j = g & 15;

    float w0[HH], wi1[HH], w1[HH];
    #pragma unroll
    for (int k = 0; k < HH; ++k) {
        w0[k]  = Whh0[g * HH + k];
        wi1[k] = Wih1[g * HH + k];
        w1[k]  = Whh1[g * HH + k];
    }
    const float bias1 = bih1[g] + bhh1[g];

    float h0v = h0in[b * HH + j];
    float h1v = h0in[BB * HH + b * HH + j];
    float c0v = c0in[b * HH + j];
    float c1v = c0in[BB * HH + b * HH + j];

    const float* xprow = xp0 + (size_t)b * TT * GG + g;

    // prologue: layer0 step 0
    {
        float aa = xprow[0], ab = 0.0f;
        #pragma unroll
        for (int k = 0; k < 8; ++k) {
            aa += __shfl(h0v, k) * w0[k];
            ab += __shfl(h0v, k + 8) * w0[k + 8];
        }
        float acc = aa + ab;
        float iv = __shfl(acc, j), fv = __shfl(acc, j + 16);
        float gv = __shfl(acc, j + 32), ov = __shfl(acc, j + 48);
        c0v = sigf(fv) * c0v + sigf(iv) * tanhfast(gv);
        h0v = sigf(ov) * tanhfast(c0v);
    }

    for (int t = 0; t < TT - 1; ++t) {
        float xpn = xprow[(size_t)(t + 1) * GG];
        float a1a = bias1, a1b = 0.0f, a1c = 0.0f, a1d = 0.0f;
        float a0a = xpn,   a0b = 0.0f;
        #pragma unroll
        for (int k = 0; k < 8; ++k) {
            float h0k  = __shfl(h0v, k);
            float h0k8 = __shfl(h0v, k + 8);
            float h1k  = __shfl(h1v, k);
            float h1k8 = __shfl(h1v, k + 8);
            a1a += h0k  * wi1[k];
            a1b += h0k8 * wi1[k + 8];
            a1c += h1k  * w1[k];
            a1d += h1k8 * w1[k + 8];
            a0a += h0k  * w0[k];
            a0b += h0k8 * w0[k + 8];
        }
        float acc1 = (a1a + a1b) + (a1c + a1d);
        float acc0 = a0a + a0b;
        float iv1 = __shfl(acc1, j), fv1 = __shfl(acc1, j + 16);
        float gv1 = __shfl(acc1, j + 32), ov1 = __shfl(acc1, j + 48);
        float iv0 = __shfl(acc0, j), fv0 = __shfl(acc0, j + 16);
        float gv0 = __shfl(acc0, j + 32), ov0 = __shfl(acc0, j + 48);
        c1v = sigf(fv1) * c1v + sigf(iv1) * tanhfast(gv1);
        h1v = sigf(ov1) * tanhfast(c1v);
        c0v = sigf(fv0) * c0v + sigf(iv0) * tanhfast(gv0);
        h0v = sigf(ov0) * tanhfast(c0v);
        if (g < HH) y1[(size_t)(b * TT + t) * HH + g] = h1v;
    }

    // epilogue: layer1 step TT-1
    {
        float a1a = bias1, a1b = 0.0f, a1c = 0.0f, a1d = 0.0f;
        #pragma unroll
        for (int k = 0; k < 8; ++k) {
            float h0k  = __shfl(h0v, k);
            float h0k8 = __shfl(h0v, k + 8);
            float h1k  = __shfl(h1v, k);
            float h1k8 = __shfl(h1v, k + 8);
            a1a += h0k  * wi1[k];
            a1b += h0k8 * wi1[k + 8];
            a1c += h1k  * w1[k];
            a1d += h1k8 * w1[k + 8];
        }
        float acc1 = (a1a + a1b) + (a1c + a1d);
        float iv1 = __shfl(acc1, j), fv1 = __shfl(acc1, j + 16);
        float gv1 = __shfl(acc1, j + 32), ov1 = __shfl(acc1, j + 48);
        c1v = sigf(fv1) * c1v + sigf(iv1) * tanhfast(gv1);
        h1v = sigf(ov1) * tanhfast(c1v);
        if (g < HH) y1[(size_t)(b * TT + TT - 1) * HH + g] = h1v;
    }

    if (g < HH) {
        outTail[b * HH + g]               = h0v;
        outTail[BB * HH + b * HH + g]     = h1v;
        outTail[2 * BB * HH + b * HH + g] = c0v;
        outTail[3 * BB * HH + b * HH + g] = c1v;
    }
}

// ---------------- Kernel 3: FC head (write-bound), 32 rows per block ----------------
__global__ __launch_bounds__(256) void fc_kernel(const float* __restrict__ y1,
                          const float* __restrict__ fcw, const float* __restrict__ fcb,
                          float* __restrict__ out) {
    __shared__ float ys[32 * HH];                 // 512 floats
    const int tid  = threadIdx.x;
    const int v0   = blockIdx.x * 1024 + tid * 4;
    const int row0 = blockIdx.y * 32;

    ys[tid]       = y1[row0 * HH + tid];
    ys[tid + 256] = y1[row0 * HH + 256 + tid];
    __syncthreads();

    if (v0 >= VV) return;

    float w[4][HH];
    #pragma unroll
    for (int jj = 0; jj < 4; ++jj) {
        const float4* wp = reinterpret_cast<const float4*>(fcw + (size_t)(v0 + jj) * HH);
        float4 a = wp[0], b = wp[1], c = wp[2], d = wp[3];
        w[jj][0]=a.x; w[jj][1]=a.y; w[jj][2]=a.z; w[jj][3]=a.w;
        w[jj][4]=b.x; w[jj][5]=b.y; w[jj][6]=b.z; w[jj][7]=b.w;
        w[jj][8]=c.x; w[jj][9]=c.y; w[jj][10]=c.z; w[jj][11]=c.w;
        w[jj][12]=d.x; w[jj][13]=d.y; w[jj][14]=d.z; w[jj][15]=d.w;
    }
    const float4 bias = *reinterpret_cast<const float4*>(fcb + v0);
    const f32x4* ysv = reinterpret_cast<const f32x4*>(ys);

    float* orow = out + (size_t)row0 * VV + v0;
    #pragma unroll 4
    for (int r = 0; r < 32; ++r) {
        f32x4 y0 = ysv[r * 4 + 0];
        f32x4 y1v = ysv[r * 4 + 1];
        f32x4 y2 = ysv[r * 4 + 2];
        f32x4 y3 = ysv[r * 4 + 3];
        float a0 = bias.x, a1 = bias.y, a2 = bias.z, a3 = bias.w;
        #pragma unroll
        for (int jj = 0; jj < 4; ++jj) {
            float* wj = w[jj];
            float acc = y0.x*wj[0] + y0.y*wj[1] + y0.z*wj[2] + y0.w*wj[3]
                      + y1v.x*wj[4] + y1v.y*wj[5] + y1v.z*wj[6] + y1v.w*wj[7]
                      + y2.x*wj[8] + y2.y*wj[9] + y2.z*wj[10] + y2.w*wj[11]
                      + y3.x*wj[12] + y3.y*wj[13] + y3.z*wj[14] + y3.w*wj[15];
            if (jj == 0) a0 += acc;
            else if (jj == 1) a1 += acc;
            else if (jj == 2) a2 += acc;
            else a3 += acc;
        }
        f32x4 o;
        o.x = a0; o.y = a1; o.z = a2; o.w = a3;
        __builtin_nontemporal_store(o, reinterpret_cast<f32x4*>(orow));
        orow += VV;
    }
}

extern "C" void kernel_launch(void* const* d_in, const int* in_sizes, int n_in,
                              void* d_out, int out_size, void* d_ws, size_t ws_size,
                              hipStream_t stream) {
    const float* x    = (const float*)d_in[0];
    const float* h0   = (const float*)d_in[1];
    const float* c0   = (const float*)d_in[2];
    const float* emb  = (const float*)d_in[3];
    const float* Wih0 = (const float*)d_in[4];
    const float* Whh0 = (const float*)d_in[5];
    const float* bih0 = (const float*)d_in[6];
    const float* bhh0 = (const float*)d_in[7];
    const float* Wih1 = (const float*)d_in[8];
    const float* Whh1 = (const float*)d_in[9];
    const float* bih1 = (const float*)d_in[10];
    const float* bhh1 = (const float*)d_in[11];
    const float* fcw  = (const float*)d_in[12];
    const float* fcb  = (const float*)d_in[13];

    float* out = (float*)d_out;
    float* xp0 = (float*)d_ws;                          // NROWS*64 floats (+1 pad row)
    float* y1  = xp0 + (size_t)NROWS * GG + GG;         // NROWS*16 floats
    float* outTail = out + (size_t)NROWS * VV;          // hN then cN

    embed_xproj0<<<NROWS / RPB, 256, 0, stream>>>(x, emb, Wih0, bih0, bhh0, xp0);
    recurrence<<<BB, 64, 0, stream>>>(xp0, h0, c0, Whh0, Wih1, Whh1, bih1, bhh1, y1, outTail);
    fc_kernel<<<dim3(32, NROWS / 32), 256, 0, stream>>>(y1, fcw, fcb, out);
}